// Round 4
// baseline (1446.719 us; speedup 1.0000x reference)
//
#include <hip/hip_runtime.h>

// Problem constants (z: [32,256,32,32] fp32, codebook: [1024,256] fp32)
constexpr int D_ = 256;    // latent dim
constexpr int K_ = 1024;   // codebook size
constexpr int P_ = 1024;   // H*W
constexpr int N_ = 32768;  // B*H*W rows

// d_out layout (float32): z_q [8388608] ++ idx-as-float [32768] ++ loss [1]
constexpr int IDX_OFF  = 8388608;
constexpr int LOSS_OFF = 8421376;

// ---------------------------------------------------------------------------
// pass0: cnorm[k] = ||codebook[k]||^2 -> parked in out[0..1023] (z_q region,
// overwritten later by gather). Also zero the loss slot.
__global__ __launch_bounds__(64) void vq_prep(const float* __restrict__ cb,
                                              float* __restrict__ out) {
  const int k = blockIdx.x;
  const int lane = threadIdx.x;
  const float* row = cb + (size_t)k * D_;
  double s = 0.0;
  #pragma unroll
  for (int i = 0; i < D_ / 64; ++i) {
    double v = (double)row[lane + i * 64];
    s = fma(v, v, s);
  }
  #pragma unroll
  for (int off = 32; off; off >>= 1) s += __shfl_down(s, off, 64);
  if (lane == 0) out[k] = (float)s;
  if (k == 0 && lane == 0) out[LOSS_OFF] = 0.0f;
}

// ---------------------------------------------------------------------------
// pass1: scalar-broadcast distance + argmin (bit-identical arithmetic to the
// Round-2 passing kernel). Lane = row (64 rows/block, same b); each of the
// 4 waves owns 64 k's per chunk via wave-uniform codebook pointers
// (-> s_load_dwordx8 on the SMEM pipe; inner loop is pure v_fmac_f32 with
// one SGPR operand). Score s = fl32(zn + cn_k) - 2*dot_k, global
// first-index tie-break (fp32 quantization at ulp(~256) makes ties common).
//
// __launch_bounds__(256, 2): grid = 512 blocks = 2 blocks/CU max, so cap
// occupancy at 2 waves/EU -> ~256 VGPR budget. Round 2's failure was this
// exact knob: default bounds targeted 8 waves/EU -> 56 VGPRs -> acc[64]
// spilled to scratch -> VALUBusy 11.7%.
__global__ __launch_bounds__(256, 2) void vq_argmin(const float* __restrict__ z,
                                                    const float* __restrict__ cb,
                                                    const float* __restrict__ cnorm,
                                                    float* __restrict__ idxf) {
  const int tid = threadIdx.x;
  const int lane = tid & 63;
  const int w = __builtin_amdgcn_readfirstlane(tid >> 6);
  const int n0 = blockIdx.x * 64;
  const int b = n0 >> 10;
  const int p0 = n0 & (P_ - 1);
  const float* zrow = z + (size_t)b * (D_ * P_) + p0 + lane;  // + c*P_

  // per-row ||z||^2 in fp32 (8 partials + tree combine) — same order as the
  // passing Round-2 kernel -> bit-identical zn.
  float zsq[8];
  #pragma unroll
  for (int i = 0; i < 8; ++i) zsq[i] = 0.0f;
  for (int oct = 0; oct < 32; ++oct) {
    #pragma unroll
    for (int i = 0; i < 8; ++i) {
      float v = zrow[(size_t)(oct * 8 + i) * P_];
      zsq[i] = fmaf(v, v, zsq[i]);
    }
  }
  const float zn = ((zsq[0] + zsq[1]) + (zsq[2] + zsq[3])) +
                   ((zsq[4] + zsq[5]) + (zsq[6] + zsq[7]));

  float m1 = 1e30f;
  int i1 = 0x7fffffff;

  for (int kc = 0; kc < 4; ++kc) {
    const int kbase = kc * 256 + w * 64;
    float acc[64];
    #pragma unroll
    for (int j = 0; j < 64; ++j) acc[j] = 0.0f;

    // software-pipelined z loads (8 c's per step, 32 steps over D=256)
    float zr[8], znx[8];
    #pragma unroll
    for (int i = 0; i < 8; ++i) zr[i] = zrow[(size_t)i * P_];

    for (int oct = 0; oct < 32; ++oct) {
      if (oct < 31) {
        #pragma unroll
        for (int i = 0; i < 8; ++i) znx[i] = zrow[(size_t)((oct + 1) * 8 + i) * P_];
      }
      #pragma unroll
      for (int j = 0; j < 64; ++j) {
        const float* cbp = cb + (size_t)(kbase + j) * D_ + oct * 8;  // uniform -> s_load
        #pragma unroll
        for (int i = 0; i < 8; ++i) acc[j] = fmaf(zr[i], cbp[i], acc[j]);
      }
      #pragma unroll
      for (int i = 0; i < 8; ++i) zr[i] = znx[i];
    }

    // k ascends within this wave's sequence -> strict < keeps first index
    #pragma unroll
    for (int j = 0; j < 64; ++j) {
      float A = zn + cnorm[kbase + j];   // fl32 (matches reference order)
      float s = A - 2.0f * acc[j];       // fl32; 2*acc exact
      if (s < m1) { m1 = s; i1 = kbase + j; }
    }
  }

  // merge the 4 waves' (m1, i1) per row with value-then-first-index tie-break
  __shared__ float sm1[4][64];
  __shared__ int   si1[4][64];
  sm1[w][lane] = m1; si1[w][lane] = i1;
  __syncthreads();
  if (tid < 64) {
    float M1 = sm1[0][lane];
    int   I1 = si1[0][lane];
    #pragma unroll
    for (int ww = 1; ww < 4; ++ww) {
      float a1 = sm1[ww][lane];
      int   ai = si1[ww][lane];
      if (a1 < M1 || (a1 == M1 && ai < I1)) { M1 = a1; I1 = ai; }
    }
    idxf[n0 + lane] = (float)I1;
  }
}

// ---------------------------------------------------------------------------
// pass2: gather z_q = codebook[idx] into NCHW + loss. STE write replicates
// the reference's fp32 rounding exactly: out = z + (v - z).
__global__ __launch_bounds__(256) void vq_gather(const float* __restrict__ z,
                                                 const float* __restrict__ cb,
                                                 const float* __restrict__ idxf,
                                                 float* __restrict__ out,
                                                 float* __restrict__ loss) {
  const int tid = threadIdx.x;
  const int lane = tid & 63;
  const int w = tid >> 6;
  const int n0 = blockIdx.x * 64;
  const int b = n0 >> 10;
  const int p0 = n0 & (P_ - 1);
  const int p = p0 + lane;

  const int idx = (int)(idxf[n0 + lane] + 0.5f);
  const float* crow = cb + (size_t)idx * D_;
  const size_t base = (size_t)b * (D_ * P_) + p;

  float acc = 0.0f;
  #pragma unroll 4
  for (int ci = 0; ci < 64; ++ci) {
    const int c = w + ci * 4;
    const float v = crow[c];          // gather (1 MB table, L1/L2 resident)
    const size_t a = base + (size_t)c * P_;
    const float zv = z[a];
    const float d = v - zv;           // fl32
    out[a] = zv + d;                  // fl32 STE: z + sg(z_q - z), bit-exact
    acc = fmaf(d, d, acc);
  }
  #pragma unroll
  for (int off = 32; off; off >>= 1) acc += __shfl_down(acc, off, 64);
  __shared__ float wsum[4];
  if (lane == 0) wsum[w] = acc;
  __syncthreads();
  if (tid == 0) {
    float s = wsum[0] + wsum[1] + wsum[2] + wsum[3];
    atomicAdd(loss, s * (1.25f / 8388608.0f));  // (1+BETA)/(B*H*W*C)
  }
}

// ---------------------------------------------------------------------------
extern "C" void kernel_launch(void* const* d_in, const int* in_sizes, int n_in,
                              void* d_out, int out_size, void* d_ws, size_t ws_size,
                              hipStream_t stream) {
  const float* z  = (const float*)d_in[0];
  const float* cb = (const float*)d_in[1];
  float* out = (float*)d_out;

  vq_prep<<<K_, 64, 0, stream>>>(cb, out);
  vq_argmin<<<N_ / 64, 256, 0, stream>>>(z, cb, /*cnorm=*/out, out + IDX_OFF);
  vq_gather<<<N_ / 64, 256, 0, stream>>>(z, cb, out + IDX_OFF, out, out + LOSS_OFF);
}

// Round 5
// 487.507 us; speedup vs baseline: 2.9676x; 2.9676x over previous
//
#include <hip/hip_runtime.h>

// Problem: z [32,256,32,32] fp32, codebook [1024,256] fp32
constexpr int D_ = 256;
constexpr int K_ = 1024;
constexpr int P_ = 1024;
constexpr int N_ = 32768;

// d_out layout (float32): z_q [8388608] ++ idx-as-float [32768] ++ loss [1]
constexpr int IDX_OFF  = 8388608;
constexpr int LOSS_OFF = 8421376;

// scratch parked in d_out's z_q region (gather overwrites it LAST):
// cb16sw: 64kt*8ds*2pair*64lane*8j halves = 524288 halves = 262144 floats
constexpr int CB16_OFF = 0;        // floats [0, 262144)
constexpr int CN_OFF   = 262400;   // cnorm [1024] floats (gap past prefetch overrun)
constexpr int ZN_OFF   = 263424;   // zn [32768] floats

constexpr float RESCUE_MARGIN = 1e-4f;  // ~3 ulp(256); rescues ~1.5% of rows
constexpr float FLAG = 4096.0f;

typedef _Float16 half8 __attribute__((ext_vector_type(8)));
typedef float f32x4 __attribute__((ext_vector_type(4)));

// ---------------------------------------------------------------------------
// prep: blk<512: zn[row]=||z_row||^2 (PROVEN order: 8 partials over oct, tree);
//       512..1535: cnorm[k] fp64 (proven); 1536..1599: cb fp16-split swizzle.
__global__ __launch_bounds__(64) void vq_prep(const float* __restrict__ z,
                                              const float* __restrict__ cb,
                                              float* __restrict__ scratch,
                                              float* __restrict__ loss) {
  const int blk = blockIdx.x;
  const int lane = threadIdx.x;
  if (blk < 512) {
    const int n0 = blk * 64;
    const int b = n0 >> 10, p0 = n0 & (P_ - 1);
    const float* zp = z + (size_t)b * (D_ * P_) + p0 + lane;
    float a8[8];
    #pragma unroll
    for (int i = 0; i < 8; ++i) a8[i] = 0.0f;
    for (int oct = 0; oct < 32; ++oct) {
      #pragma unroll
      for (int i = 0; i < 8; ++i) {
        float v = zp[(size_t)(oct * 8 + i) * P_];
        a8[i] = fmaf(v, v, a8[i]);
      }
    }
    scratch[ZN_OFF + n0 + lane] = ((a8[0] + a8[1]) + (a8[2] + a8[3])) +
                                  ((a8[4] + a8[5]) + (a8[6] + a8[7]));
    if (blk == 0 && lane == 0) *loss = 0.0f;
  } else if (blk < 1536) {
    const int k = blk - 512;
    const float* row = cb + (size_t)k * D_;
    double s = 0.0;
    #pragma unroll
    for (int i = 0; i < 4; ++i) {
      double v = (double)row[lane + i * 64];
      s = fma(v, v, s);
    }
    #pragma unroll
    for (int off = 32; off; off >>= 1) s += __shfl_down(s, off, 64);
    if (lane == 0) scratch[CN_OFF + k] = (float)s;
  } else {
    // swizzle codebook*1024 into fp16 (hi,lo) pairs, MFMA-B-frag lane order:
    // slot layout: ((s*2+pair)*64 + lane)*8 + j, s = kt*8+ds,
    // value = cb[kt*16 + (lane&15)][ds*32 + (lane>>4)*8 + j] * 1024
    const int kt = blk - 1536;
    const int k = kt * 16 + (lane & 15);
    const int quad = lane >> 4;
    _Float16* cw = (_Float16*)(scratch + CB16_OFF);
    for (int ds = 0; ds < 8; ++ds) {
      const float* src = cb + (size_t)k * D_ + ds * 32 + quad * 8;
      half8 h, lo;
      #pragma unroll
      for (int j = 0; j < 8; ++j) {
        const float v = src[j] * 1024.0f;      // scale: keeps lo out of subnormals
        const _Float16 hh = (_Float16)v;
        h[j] = hh;
        lo[j] = (_Float16)(v - (float)hh);
      }
      const int s = kt * 8 + ds;
      *(half8*)(cw + ((size_t)(s * 2 + 0) * 64 + lane) * 8) = h;
      *(half8*)(cw + ((size_t)(s * 2 + 1) * 64 + lane) * 8) = lo;
    }
  }
}

// ---------------------------------------------------------------------------
// main: fp16-split MFMA distance + argmin + ambiguity flag.
// Block 256 thr = 4 waves; 128 rows/block (wave w owns row-tiles 2w, 2w+1).
// A fragments (z fp16 pairs, full depth) resident in registers; B fragments
// streamed from pre-swizzled global (coalesced dwordx4, L2-hot, depth-2
// register pipeline). No LDS / barriers in the k-loop.
__global__ __launch_bounds__(256, 2) void vq_mfma(const float* __restrict__ z,
                                                  const float* __restrict__ scratch,
                                                  float* __restrict__ idxf) {
  const int t = threadIdx.x;
  const int w = t >> 6;
  const int l = t & 63;
  const int quad = l >> 4;
  const int col = l & 15;
  const int n0 = blockIdx.x * 128;
  const int b = n0 >> 10;
  const int p0 = n0 & (P_ - 1);

  const _Float16* cbsw = (const _Float16*)(scratch + CB16_OFF);
  const float* cnorm = scratch + CN_OFF;
  const float* zn = scratch + ZN_OFF;

  __shared__ float Azs[128 * 33];   // [row][d-chunk], stride 33 (conflict-free)

  // ---- stage A: 8 chunks of 32 d; build fp16-split frags in registers.
  // A-frag mapping: lane holds A[m = l&15][dslot = quad*8 + j] (same slot
  // function as B -> any slot-permutation error cancels in the dot).
  half8 Ah[2][8], Al[2][8];
  const int pp = t & 127;
  const int dl0 = t >> 7;
  for (int ds = 0; ds < 8; ++ds) {
    __syncthreads();
    #pragma unroll
    for (int i = 0; i < 16; ++i) {
      const int dloc = dl0 + 2 * i;
      Azs[pp * 33 + dloc] =
          z[(size_t)b * (D_ * P_) + (size_t)(ds * 32 + dloc) * P_ + p0 + pp];
    }
    __syncthreads();
    #pragma unroll
    for (int rt = 0; rt < 2; ++rt) {
      const int row_local = (2 * w + rt) * 16 + col;
      const float* src = &Azs[row_local * 33 + quad * 8];
      half8 h, lo;
      #pragma unroll
      for (int j = 0; j < 8; ++j) {
        const float v = src[j];
        const _Float16 hh = (_Float16)v;
        h[j] = hh;
        lo[j] = (_Float16)(v - (float)hh);
      }
      Ah[rt][ds] = h;
      Al[rt][ds] = lo;
    }
  }

  // zn for this lane's C/D rows (C/D: row = quad*4 + reg, col = l&15)
  float znr[2][4];
  #pragma unroll
  for (int rt = 0; rt < 2; ++rt)
    #pragma unroll
    for (int r = 0; r < 4; ++r)
      znr[rt][r] = zn[n0 + (2 * w + rt) * 16 + quad * 4 + r];

  float m1[2][4], m2v[2][4];
  int i1[2][4];
  #pragma unroll
  for (int rt = 0; rt < 2; ++rt)
    #pragma unroll
    for (int r = 0; r < 4; ++r) { m1[rt][r] = 1e30f; m2v[rt][r] = 1e30f; i1[rt][r] = 0; }

  // depth-2 B pipeline, slot = ds&3 (8 % 4 == 0 keeps it compile-time)
  half8 Bh[4], Bl[4];
  #pragma unroll
  for (int s = 0; s < 2; ++s) {
    Bh[s] = *(const half8*)(cbsw + ((size_t)(s * 2 + 0) * 64 + l) * 8);
    Bl[s] = *(const half8*)(cbsw + ((size_t)(s * 2 + 1) * 64 + l) * 8);
  }

  for (int kt = 0; kt < 64; ++kt) {
    f32x4 a0 = {0.f, 0.f, 0.f, 0.f};
    f32x4 a1 = {0.f, 0.f, 0.f, 0.f};
    const float cnf = cnorm[kt * 16 + col];
    #pragma unroll
    for (int ds = 0; ds < 8; ++ds) {
      const int s = kt * 8 + ds;
      const int cur = ds & 3;
      const int nx = (ds + 2) & 3;
      // prefetch s+2 (overruns past last slab into padded gap — never used)
      Bh[nx] = *(const half8*)(cbsw + ((size_t)((s + 2) * 2 + 0) * 64 + l) * 8);
      Bl[nx] = *(const half8*)(cbsw + ((size_t)((s + 2) * 2 + 1) * 64 + l) * 8);
      // 3-term split: hz*hc + hz*lc + lz*hc  (lz*lc <= 3e-8, dropped)
      a0 = __builtin_amdgcn_mfma_f32_16x16x32_f16(Ah[0][ds], Bh[cur], a0, 0, 0, 0);
      a1 = __builtin_amdgcn_mfma_f32_16x16x32_f16(Ah[1][ds], Bh[cur], a1, 0, 0, 0);
      a0 = __builtin_amdgcn_mfma_f32_16x16x32_f16(Ah[0][ds], Bl[cur], a0, 0, 0, 0);
      a1 = __builtin_amdgcn_mfma_f32_16x16x32_f16(Ah[1][ds], Bl[cur], a1, 0, 0, 0);
      a0 = __builtin_amdgcn_mfma_f32_16x16x32_f16(Al[0][ds], Bh[cur], a0, 0, 0, 0);
      a1 = __builtin_amdgcn_mfma_f32_16x16x32_f16(Al[1][ds], Bh[cur], a1, 0, 0, 0);
    }
    // epilogue: s = fl( fl(zn+cn) - acc*2^-9 )  (acc carries the 1024 scale;
    // single-rounding identical to the proven  A - 2.0f*dot  form)
    const int kg = kt * 16 + col;
    #pragma unroll
    for (int r = 0; r < 4; ++r) {
      const float s0 = fmaf(a0[r], -0x1p-9f, znr[0][r] + cnf);
      if (s0 < m1[0][r]) { m2v[0][r] = m1[0][r]; m1[0][r] = s0; i1[0][r] = kg; }
      else if (s0 < m2v[0][r]) m2v[0][r] = s0;
      const float s1 = fmaf(a1[r], -0x1p-9f, znr[1][r] + cnf);
      if (s1 < m1[1][r]) { m2v[1][r] = m1[1][r]; m1[1][r] = s1; i1[1][r] = kg; }
      else if (s1 < m2v[1][r]) m2v[1][r] = s1;
    }
  }

  // cross-lane merge over the 16 cols sharing each row; ties -> min index,
  // and an equal-valued other m1 forces m2 = m1 (margin 0 -> rescue).
  #pragma unroll
  for (int rt = 0; rt < 2; ++rt)
    #pragma unroll
    for (int r = 0; r < 4; ++r) {
      float M1 = m1[rt][r], M2 = m2v[rt][r];
      int I1 = i1[rt][r];
      #pragma unroll
      for (int off = 1; off < 16; off <<= 1) {
        const float om1 = __shfl_xor(M1, off, 64);
        const float om2 = __shfl_xor(M2, off, 64);
        const int oi1 = __shfl_xor(I1, off, 64);
        if (om1 < M1) { M2 = fminf(M1, om2); M1 = om1; I1 = oi1; }
        else if (om1 == M1) { I1 = min(I1, oi1); M2 = fminf(fminf(M2, om2), om1); }
        else { M2 = fminf(M2, om1); }
      }
      if (col == 0) {
        float res = (float)I1;
        if (M2 - M1 < RESCUE_MARGIN) res += FLAG;   // ambiguous -> exact rescore
        idxf[n0 + (2 * w + rt) * 16 + quad * 4 + r] = res;
      }
    }
}

// ---------------------------------------------------------------------------
// rescue: exact fp32 rescore of flagged rows with the PROVEN scorer
// (sequential fma over d ascending, s = (zn+cn) - 2*dot, first-index wins).
__global__ __launch_bounds__(256) void vq_rescue(const float* __restrict__ z,
                                                 const float* __restrict__ cb,
                                                 const float* __restrict__ scratch,
                                                 float* __restrict__ idxf) {
  const int tid = threadIdx.x;
  const int n0 = blockIdx.x * 64;
  const int b = n0 >> 10, p0 = n0 & (P_ - 1);
  const float* cnorm = scratch + CN_OFF;
  const float* zn = scratch + ZN_OFF;

  __shared__ float zd[D_];
  __shared__ float rv[256];
  __shared__ int ri[256];

  for (int j = 0; j < 64; ++j) {
    const float f = idxf[n0 + j];   // uniform across block
    if (f < FLAG) continue;
    const int p = p0 + j;
    zd[tid] = z[(size_t)b * (D_ * P_) + (size_t)tid * P_ + p];
    __syncthreads();
    const float zA = zn[n0 + j];
    float bv = 1e30f;
    int bi = 0x7fffffff;
    #pragma unroll
    for (int kk = 0; kk < 4; ++kk) {
      const int k = tid + kk * 256;
      const float* cr = cb + (size_t)k * D_;
      float acc = 0.0f;
      for (int c = 0; c < D_; ++c) acc = fmaf(zd[c], cr[c], acc);
      const float A = zA + cnorm[k];
      const float s = A - 2.0f * acc;
      if (s < bv || (s == bv && k < bi)) { bv = s; bi = k; }
    }
    rv[tid] = bv; ri[tid] = bi;
    __syncthreads();
    for (int off = 128; off >= 1; off >>= 1) {
      if (tid < off) {
        const float ov = rv[tid + off];
        const int oi = ri[tid + off];
        if (ov < rv[tid] || (ov == rv[tid] && oi < ri[tid])) { rv[tid] = ov; ri[tid] = oi; }
      }
      __syncthreads();
    }
    if (tid == 0) idxf[n0 + j] = (float)ri[0];
    __syncthreads();
  }
}

// ---------------------------------------------------------------------------
// gather: z_q = codebook[idx] into NCHW + loss; STE write out = z + (v - z).
__global__ __launch_bounds__(256) void vq_gather(const float* __restrict__ z,
                                                 const float* __restrict__ cb,
                                                 const float* __restrict__ idxf,
                                                 float* __restrict__ out,
                                                 float* __restrict__ loss) {
  const int tid = threadIdx.x;
  const int lane = tid & 63;
  const int w = tid >> 6;
  const int n0 = blockIdx.x * 64;
  const int b = n0 >> 10;
  const int p0 = n0 & (P_ - 1);
  const int p = p0 + lane;

  const int idx = (int)(idxf[n0 + lane] + 0.5f);
  const float* crow = cb + (size_t)idx * D_;
  const size_t base = (size_t)b * (D_ * P_) + p;

  float acc = 0.0f;
  #pragma unroll 4
  for (int ci = 0; ci < 64; ++ci) {
    const int c = w + ci * 4;
    const float v = crow[c];
    const size_t a = base + (size_t)c * P_;
    const float zv = z[a];
    const float d = v - zv;
    out[a] = zv + d;
    acc = fmaf(d, d, acc);
  }
  #pragma unroll
  for (int off = 32; off; off >>= 1) acc += __shfl_down(acc, off, 64);
  __shared__ float wsum[4];
  if (lane == 0) wsum[w] = acc;
  __syncthreads();
  if (tid == 0) {
    float s = wsum[0] + wsum[1] + wsum[2] + wsum[3];
    atomicAdd(loss, s * (1.25f / 8388608.0f));
  }
}

// ---------------------------------------------------------------------------
extern "C" void kernel_launch(void* const* d_in, const int* in_sizes, int n_in,
                              void* d_out, int out_size, void* d_ws, size_t ws_size,
                              hipStream_t stream) {
  const float* z = (const float*)d_in[0];
  const float* cb = (const float*)d_in[1];
  float* out = (float*)d_out;

  vq_prep<<<1600, 64, 0, stream>>>(z, cb, out, out + LOSS_OFF);
  vq_mfma<<<N_ / 128, 256, 0, stream>>>(z, out, out + IDX_OFF);
  vq_rescue<<<N_ / 64, 256, 0, stream>>>(z, cb, out, out + IDX_OFF);
  vq_gather<<<N_ / 64, 256, 0, stream>>>(z, cb, out + IDX_OFF, out, out + LOSS_OFF);
}

// Round 6
// 287.702 us; speedup vs baseline: 5.0285x; 1.6945x over previous
//
#include <hip/hip_runtime.h>

// Problem: z [32,256,32,32] fp32, codebook [1024,256] fp32
constexpr int D_ = 256;
constexpr int K_ = 1024;
constexpr int P_ = 1024;
constexpr int N_ = 32768;

// d_out layout (float32): z_q [8388608] ++ idx-as-float [32768] ++ loss [1]
constexpr int IDX_OFF  = 8388608;
constexpr int LOSS_OFF = 8421376;

// scratch parked in d_out's z_q region (gather overwrites it LAST):
constexpr int CB16_OFF = 0;        // fp16-split swizzled cb: 262144 floats
constexpr int CN_OFF   = 262400;   // cnorm [1024]  (gap absorbs B prefetch overrun)
constexpr int ZN_OFF   = 263424;   // zn [32768]
constexpr int CNT_OFF  = 296448;   // worklist counter (int)
constexpr int WL_OFF   = 296449;   // worklist [<=32768] (int row ids)

constexpr float RESCUE_MARGIN = 1e-4f;  // ~3.3 ulp(256); flags ~1% of rows

typedef _Float16 half8 __attribute__((ext_vector_type(8)));
typedef float f32x4 __attribute__((ext_vector_type(4)));

// ---------------------------------------------------------------------------
// prep: blk<512: zn[row]=||z||^2 (PROVEN bit order); 512..1535: cnorm fp64
// (proven); 1536..1599: cb fp16-split swizzle. blk0 zeroes loss + counter.
__global__ __launch_bounds__(64) void vq_prep(const float* __restrict__ z,
                                              const float* __restrict__ cb,
                                              float* __restrict__ scratch,
                                              float* __restrict__ loss) {
  const int blk = blockIdx.x;
  const int lane = threadIdx.x;
  if (blk < 512) {
    const int n0 = blk * 64;
    const int b = n0 >> 10, p0 = n0 & (P_ - 1);
    const float* zp = z + (size_t)b * (D_ * P_) + p0 + lane;
    float a8[8];
    #pragma unroll
    for (int i = 0; i < 8; ++i) a8[i] = 0.0f;
    for (int oct = 0; oct < 32; ++oct) {
      #pragma unroll
      for (int i = 0; i < 8; ++i) {
        float v = zp[(size_t)(oct * 8 + i) * P_];
        a8[i] = fmaf(v, v, a8[i]);
      }
    }
    scratch[ZN_OFF + n0 + lane] = ((a8[0] + a8[1]) + (a8[2] + a8[3])) +
                                  ((a8[4] + a8[5]) + (a8[6] + a8[7]));
    if (blk == 0 && lane == 0) {
      *loss = 0.0f;
      ((int*)(scratch + CNT_OFF))[0] = 0;
    }
  } else if (blk < 1536) {
    const int k = blk - 512;
    const float* row = cb + (size_t)k * D_;
    double s = 0.0;
    #pragma unroll
    for (int i = 0; i < 4; ++i) {
      double v = (double)row[lane + i * 64];
      s = fma(v, v, s);
    }
    #pragma unroll
    for (int off = 32; off; off >>= 1) s += __shfl_down(s, off, 64);
    if (lane == 0) scratch[CN_OFF + k] = (float)s;
  } else {
    // swizzle codebook*1024 into fp16 (hi,lo) pairs, MFMA-B-frag lane order:
    // slot ((s*2+pair)*64 + lane)*8 + j, s = kt*8+ds,
    // value = cb[kt*16 + (lane&15)][ds*32 + (lane>>4)*8 + j] * 1024
    const int kt = blk - 1536;
    const int k = kt * 16 + (lane & 15);
    const int quad = lane >> 4;
    _Float16* cw = (_Float16*)(scratch + CB16_OFF);
    for (int ds = 0; ds < 8; ++ds) {
      const float* src = cb + (size_t)k * D_ + ds * 32 + quad * 8;
      half8 h, lo;
      #pragma unroll
      for (int j = 0; j < 8; ++j) {
        const float v = src[j] * 1024.0f;   // scale keeps lo out of subnormals
        const _Float16 hh = (_Float16)v;
        h[j] = hh;
        lo[j] = (_Float16)(v - (float)hh);
      }
      const int s = kt * 8 + ds;
      *(half8*)(cw + ((size_t)(s * 2 + 0) * 64 + lane) * 8) = h;
      *(half8*)(cw + ((size_t)(s * 2 + 1) * 64 + lane) * 8) = lo;
    }
  }
}

// ---------------------------------------------------------------------------
// main: fp16-split MFMA distance + argmin + worklist flagging.
// Block 256 thr = 4 waves, 64 rows (4 row-tiles of 16). Wave w owns row-tiles
// (w&1)*2+{0,1} and K-half (w>>1): waves 0,1 -> kt 0..31, waves 2,3 -> 32..63.
// Grid 512 = 2 blocks/CU = 2 waves/SIMD (4 MFMA chains/SIMD -> issue-limited).
__global__ __launch_bounds__(256, 2) void vq_mfma(const float* __restrict__ z,
                                                  float* __restrict__ scratch,
                                                  float* __restrict__ idxf) {
  const int t = threadIdx.x;
  const int w = t >> 6;
  const int l = t & 63;
  const int quad = l >> 4;
  const int col = l & 15;
  const int half = w >> 1;
  const int rpair = w & 1;          // which 32-row half of the block
  const int n0 = blockIdx.x * 64;
  const int b = n0 >> 10;
  const int p0 = n0 & (P_ - 1);

  const _Float16* cbsw = (const _Float16*)(scratch + CB16_OFF);
  const float* cnorm = scratch + CN_OFF;
  const float* zn = scratch + ZN_OFF;

  __shared__ float Azs[64 * 33];    // [p][d-chunk], stride 33 (<=2-way, free)
  __shared__ float sm1[2][64], sm2[2][64];
  __shared__ int   si1[2][64];

  // ---- stage A: 8 chunks of 32 d; build fp16-split frags in registers.
  // A-frag: lane holds A[m=col][dslot=quad*8+j] — same slot function as B,
  // so slot-permutation errors cancel in the dot.
  half8 Ah[2][8], Al[2][8];
  const int pp = t & 63;
  const int dl0 = (t >> 6) * 8;
  for (int ds = 0; ds < 8; ++ds) {
    __syncthreads();
    #pragma unroll
    for (int i = 0; i < 8; ++i) {
      const int dloc = dl0 + i;
      Azs[pp * 33 + dloc] =
          z[(size_t)b * (D_ * P_) + (size_t)(ds * 32 + dloc) * P_ + p0 + pp];
    }
    __syncthreads();
    #pragma unroll
    for (int rt = 0; rt < 2; ++rt) {
      const int row_local = (rpair * 2 + rt) * 16 + col;
      const float* src = &Azs[row_local * 33 + quad * 8];
      half8 h, lo;
      #pragma unroll
      for (int j = 0; j < 8; ++j) {
        const float v = src[j];
        const _Float16 hh = (_Float16)v;
        h[j] = hh;
        lo[j] = (_Float16)(v - (float)hh);
      }
      Ah[rt][ds] = h;
      Al[rt][ds] = lo;
    }
  }

  // zn for this lane's C/D rows (C/D: row = quad*4 + r, col = l&15)
  float znr[2][4];
  #pragma unroll
  for (int rt = 0; rt < 2; ++rt)
    #pragma unroll
    for (int r = 0; r < 4; ++r)
      znr[rt][r] = zn[n0 + (rpair * 2 + rt) * 16 + quad * 4 + r];

  float m1[2][4], m2v[2][4];
  int i1[2][4];
  #pragma unroll
  for (int rt = 0; rt < 2; ++rt)
    #pragma unroll
    for (int r = 0; r < 4; ++r) { m1[rt][r] = 1e30f; m2v[rt][r] = 1e30f; i1[rt][r] = 0; }

  const int kt0 = half * 32;
  // depth-2 B register pipeline, slot = ds&3
  half8 Bh[4], Bl[4];
  #pragma unroll
  for (int s = 0; s < 2; ++s) {
    const int sg = kt0 * 8 + s;
    Bh[s] = *(const half8*)(cbsw + ((size_t)(sg * 2 + 0) * 64 + l) * 8);
    Bl[s] = *(const half8*)(cbsw + ((size_t)(sg * 2 + 1) * 64 + l) * 8);
  }

  for (int kt = kt0; kt < kt0 + 32; ++kt) {
    f32x4 a0 = {0.f, 0.f, 0.f, 0.f};
    f32x4 a1 = {0.f, 0.f, 0.f, 0.f};
    const float cnf = cnorm[kt * 16 + col];
    #pragma unroll
    for (int ds = 0; ds < 8; ++ds) {
      const int s = kt * 8 + ds;
      const int cur = ds & 3;
      const int nx = (ds + 2) & 3;
      // prefetch s+2 (end-of-range overrun reads unused scratch — harmless)
      Bh[nx] = *(const half8*)(cbsw + ((size_t)((s + 2) * 2 + 0) * 64 + l) * 8);
      Bl[nx] = *(const half8*)(cbsw + ((size_t)((s + 2) * 2 + 1) * 64 + l) * 8);
      // 3-term split: hz*hc + hz*lc + lz*hc  (lz*lc <= 5e-8 in score, dropped)
      a0 = __builtin_amdgcn_mfma_f32_16x16x32_f16(Ah[0][ds], Bh[cur], a0, 0, 0, 0);
      a1 = __builtin_amdgcn_mfma_f32_16x16x32_f16(Ah[1][ds], Bh[cur], a1, 0, 0, 0);
      a0 = __builtin_amdgcn_mfma_f32_16x16x32_f16(Ah[0][ds], Bl[cur], a0, 0, 0, 0);
      a1 = __builtin_amdgcn_mfma_f32_16x16x32_f16(Ah[1][ds], Bl[cur], a1, 0, 0, 0);
      a0 = __builtin_amdgcn_mfma_f32_16x16x32_f16(Al[0][ds], Bh[cur], a0, 0, 0, 0);
      a1 = __builtin_amdgcn_mfma_f32_16x16x32_f16(Al[1][ds], Bh[cur], a1, 0, 0, 0);
    }
    // s = fl( fl(zn+cn) - acc*2^-9 )  — same fp32 grid as the reference
    const int kg = kt * 16 + col;
    #pragma unroll
    for (int r = 0; r < 4; ++r) {
      const float s0 = fmaf(a0[r], -0x1p-9f, znr[0][r] + cnf);
      if (s0 < m1[0][r]) { m2v[0][r] = m1[0][r]; m1[0][r] = s0; i1[0][r] = kg; }
      else if (s0 < m2v[0][r]) m2v[0][r] = s0;
      const float s1 = fmaf(a1[r], -0x1p-9f, znr[1][r] + cnf);
      if (s1 < m1[1][r]) { m2v[1][r] = m1[1][r]; m1[1][r] = s1; i1[1][r] = kg; }
      else if (s1 < m2v[1][r]) m2v[1][r] = s1;
    }
  }

  // intra-wave merge over the 16 cols of each row (ties -> min index;
  // duplicate m1 value forces m2 = m1 -> margin 0 -> rescue)
  #pragma unroll
  for (int rt = 0; rt < 2; ++rt)
    #pragma unroll
    for (int r = 0; r < 4; ++r) {
      float M1 = m1[rt][r], M2 = m2v[rt][r];
      int I1 = i1[rt][r];
      #pragma unroll
      for (int off = 1; off < 16; off <<= 1) {
        const float om1 = __shfl_xor(M1, off, 64);
        const float om2 = __shfl_xor(M2, off, 64);
        const int oi1 = __shfl_xor(I1, off, 64);
        if (om1 < M1) { M2 = fminf(M1, om2); M1 = om1; I1 = oi1; }
        else if (om1 == M1) { I1 = min(I1, oi1); M2 = fminf(fminf(M2, om2), om1); }
        else { M2 = fminf(M2, om1); }
      }
      if (col == 0) {
        const int row_local = (rpair * 2 + rt) * 16 + quad * 4 + r;
        sm1[half][row_local] = M1;
        sm2[half][row_local] = M2;
        si1[half][row_local] = I1;
      }
    }
  __syncthreads();

  // cross-half merge (half 0 covers k<512, half 1 k>=512; half-0 wins ties)
  if (t < 64) {
    const float a1v = sm1[0][t], a2v = sm2[0][t];
    const int ai = si1[0][t];
    const float b1v = sm1[1][t], b2v = sm2[1][t];
    const int bi = si1[1][t];
    float M1, M2; int I1;
    if (b1v < a1v)      { M1 = b1v; I1 = bi; M2 = fminf(a1v, b2v); }
    else if (b1v == a1v){ M1 = a1v; I1 = ai; M2 = M1; }           // tie -> rescue
    else                { M1 = a1v; I1 = ai; M2 = fminf(a2v, b1v); }
    idxf[n0 + t] = (float)I1;
    if (M2 - M1 < RESCUE_MARGIN) {
      int* cnt = (int*)(scratch + CNT_OFF);
      int* wl = (int*)(scratch + WL_OFF);
      const int pos = atomicAdd(cnt, 1);
      wl[pos] = n0 + t;
    }
  }
}

// ---------------------------------------------------------------------------
// rescue: exact fp32 rescore of worklisted rows with the PROVEN scorer
// (ascending sequential fma over d; s = (zn+cn) - 2*dot; first index wins).
// One block per row, blocks stride the worklist.
__global__ __launch_bounds__(256) void vq_rescue(const float* __restrict__ z,
                                                 const float* __restrict__ cb,
                                                 const float* __restrict__ scratch,
                                                 float* __restrict__ idxf) {
  const int tid = threadIdx.x;
  const float* cnorm = scratch + CN_OFF;
  const float* zn = scratch + ZN_OFF;
  const int count = ((const int*)(scratch + CNT_OFF))[0];
  const int* wl = (const int*)(scratch + WL_OFF);

  __shared__ float zd[D_];
  __shared__ float rv[256];
  __shared__ int ri[256];

  for (int wi = blockIdx.x; wi < count; wi += gridDim.x) {
    const int n = wl[wi];
    const int b = n >> 10, p = n & (P_ - 1);
    zd[tid] = z[(size_t)b * (D_ * P_) + (size_t)tid * P_ + p];
    __syncthreads();
    const float zA = zn[n];
    float bv = 1e30f;
    int bi = 0x7fffffff;
    #pragma unroll
    for (int kk = 0; kk < 4; ++kk) {
      const int k = tid + kk * 256;
      const float4* cr4 = (const float4*)(cb + (size_t)k * D_);
      float acc = 0.0f;
      #pragma unroll 4
      for (int c4 = 0; c4 < 64; ++c4) {
        const float4 v = cr4[c4];           // vector load; fma order unchanged
        acc = fmaf(zd[c4 * 4 + 0], v.x, acc);
        acc = fmaf(zd[c4 * 4 + 1], v.y, acc);
        acc = fmaf(zd[c4 * 4 + 2], v.z, acc);
        acc = fmaf(zd[c4 * 4 + 3], v.w, acc);
      }
      const float A = zA + cnorm[k];
      const float s = A - 2.0f * acc;
      if (s < bv || (s == bv && k < bi)) { bv = s; bi = k; }
    }
    rv[tid] = bv; ri[tid] = bi;
    __syncthreads();
    for (int off = 128; off >= 1; off >>= 1) {
      if (tid < off) {
        const float ov = rv[tid + off];
        const int oi = ri[tid + off];
        if (ov < rv[tid] || (ov == rv[tid] && oi < ri[tid])) { rv[tid] = ov; ri[tid] = oi; }
      }
      __syncthreads();
    }
    if (tid == 0) idxf[n] = (float)ri[0];
    __syncthreads();
  }
}

// ---------------------------------------------------------------------------
// gather: z_q = codebook[idx] into NCHW + loss; STE write out = z + (v - z).
// float4 gather loads (4x fewer VMEM instructions, same L2 lines).
__global__ __launch_bounds__(256) void vq_gather(const float* __restrict__ z,
                                                 const float* __restrict__ cb,
                                                 const float* __restrict__ idxf,
                                                 float* __restrict__ out,
                                                 float* __restrict__ loss) {
  const int tid = threadIdx.x;
  const int lane = tid & 63;
  const int w = tid >> 6;
  const int n0 = blockIdx.x * 64;
  const int b = n0 >> 10;
  const int p0 = n0 & (P_ - 1);
  const int p = p0 + lane;

  const int idx = (int)(idxf[n0 + lane] + 0.5f);
  const float4* crow4 = (const float4*)(cb + (size_t)idx * D_);
  const size_t base = (size_t)b * (D_ * P_) + p;

  float acc = 0.0f;
  #pragma unroll 4
  for (int ci = 0; ci < 16; ++ci) {
    const float4 v = crow4[w * 16 + ci];
    const int c = w * 64 + ci * 4;
    const float vv[4] = {v.x, v.y, v.z, v.w};
    #pragma unroll
    for (int u = 0; u < 4; ++u) {
      const size_t a = base + (size_t)(c + u) * P_;
      const float zv = z[a];
      const float d = vv[u] - zv;
      out[a] = zv + d;                  // fl32 STE, bit-exact
      acc = fmaf(d, d, acc);
    }
  }
  #pragma unroll
  for (int off = 32; off; off >>= 1) acc += __shfl_down(acc, off, 64);
  __shared__ float wsum[4];
  if (lane == 0) wsum[w] = acc;
  __syncthreads();
  if (tid == 0) {
    float s = wsum[0] + wsum[1] + wsum[2] + wsum[3];
    atomicAdd(loss, s * (1.25f / 8388608.0f));
  }
}

// ---------------------------------------------------------------------------
extern "C" void kernel_launch(void* const* d_in, const int* in_sizes, int n_in,
                              void* d_out, int out_size, void* d_ws, size_t ws_size,
                              hipStream_t stream) {
  const float* z = (const float*)d_in[0];
  const float* cb = (const float*)d_in[1];
  float* out = (float*)d_out;

  vq_prep<<<1600, 64, 0, stream>>>(z, cb, out, out + LOSS_OFF);
  vq_mfma<<<N_ / 64, 256, 0, stream>>>(z, out, out + IDX_OFF);
  vq_rescue<<<512, 256, 0, stream>>>(z, cb, out, out + IDX_OFF);
  vq_gather<<<N_ / 64, 256, 0, stream>>>(z, cb, out + IDX_OFF, out, out + LOSS_OFF);
}